// Round 12
// baseline (99.082 us; speedup 1.0000x reference)
//
#include <hip/hip_runtime.h>
#include <math.h>

#define BB 4
#define NN 2048
#define DD 512
#define LAMBDA_INIT 0.8f
#define EPSV 1e-5f

typedef __attribute__((ext_vector_type(8))) short bf16x8;
typedef __attribute__((ext_vector_type(4))) float f32x4;
typedef __attribute__((ext_vector_type(16))) float f32x16;
typedef unsigned short u16;
typedef __attribute__((ext_vector_type(4))) u16 u16x4;
typedef __attribute__((ext_vector_type(8))) u16 u16x8;
typedef __attribute__((ext_vector_type(4))) unsigned u32x4;

__device__ __forceinline__ u16 f2bf(float f) {
  unsigned u = __builtin_bit_cast(unsigned, f);
  u = (u + 0x7FFFu + ((u >> 16) & 1u)) >> 16;
  return (u16)u;
}

__device__ __forceinline__ void gload16(const void* g, void* l) {
  __builtin_amdgcn_global_load_lds((const __attribute__((address_space(1))) unsigned*)g,
                                   (__attribute__((address_space(3))) unsigned*)l, 16, 0, 0);
}

__device__ __forceinline__ f32x16 fz16() {
  f32x16 z;
  #pragma unroll
  for (int i = 0; i < 16; ++i) z[i] = 0.f;
  return z;
}

__device__ __forceinline__ void plswap(unsigned &a, unsigned &b) {
  asm("v_permlane32_swap_b32 %0, %1" : "+v"(a), "+v"(b));
}
__device__ __forceinline__ float xhalf_add(float x) {
  unsigned a = __builtin_bit_cast(unsigned, x), b;
  asm("v_mov_b32 %0, %1" : "=v"(b) : "v"(a));
  asm("v_permlane32_swap_b32 %0, %1" : "+v"(a), "+v"(b));
  return __builtin_bit_cast(float, a) + __builtin_bit_cast(float, b);
}

// ---- prepass: Q bf16 (scaled 0.125*log2e), K bf16 pre-swizzled rows, W bf16 ----
__global__ __launch_bounds__(256) void prep_kernel(
    const float* __restrict__ q, const float* __restrict__ k, const float* __restrict__ w,
    u16* __restrict__ Qb, u16* __restrict__ Kb, u16* __restrict__ Wb)
{
  const int t = threadIdx.x;
  const int bid = blockIdx.x;
  if (bid >= BB * NN) {
    const size_t idx = (size_t)(bid - BB * NN) * 256 + t;
    float4 f = *(const float4*)&w[idx * 4];
    u16x4 o = { f2bf(f.x), f2bf(f.y), f2bf(f.z), f2bf(f.w) };
    *(u16x4*)&Wb[idx * 4] = o;
    return;
  }
  const size_t row = bid;
  const int n = bid & (NN - 1);
  const int b = bid >> 11;
  if (t < 128) {
    const float s = 0.125f * 1.4426950408889634f;
    float4 f = *(const float4*)&q[row * DD + t * 4];
    u16x4 o = { f2bf(f.x * s), f2bf(f.y * s), f2bf(f.z * s), f2bf(f.w * s) };
    *(u16x4*)&Qb[row * DD + t * 4] = o;
  } else {
    const int f0 = (t - 128) * 4;
    float4 f = *(const float4*)&k[row * DD + f0];
    const int he = f0 >> 7, fi = f0 & 127;
    const int gi = fi >> 3, lo = fi & 7;
    const int gi2 = (gi & 8) | ((gi & 7) ^ (n & 7));
    u16x4 o = { f2bf(f.x), f2bf(f.y), f2bf(f.z), f2bf(f.w) };
    *(u16x4*)&Kb[((size_t)(b * 4 + he) * NN + n) * 128 + gi2 * 8 + lo] = o;
  }
}

// ---- prepass: V tile-image (8KB per 32-kv tile, staged linearly) ----
__global__ __launch_bounds__(256) void v_prep_kernel(const float* __restrict__ v, u16* __restrict__ Vbt) {
  __shared__ u16 Ls[64][72];
  const int t = threadIdx.x;
  const int n0 = blockIdx.x * 64;
  const int d0 = blockIdx.y * 64;
  const int z  = blockIdx.z;             // b*4+he
  #pragma unroll
  for (int p = 0; p < 4; ++p) {
    int n = p * 16 + (t >> 4), f4 = t & 15;
    float4 rv = *(const float4*)&v[((size_t)((z >> 2) * NN + n0 + n)) * DD + (z & 3) * 128 + d0 + f4 * 4];
    Ls[n][f4*4+0] = f2bf(rv.x); Ls[n][f4*4+1] = f2bf(rv.y);
    Ls[n][f4*4+2] = f2bf(rv.z); Ls[n][f4*4+3] = f2bf(rv.w);
  }
  __syncthreads();
  #pragma unroll
  for (int rep = 0; rep < 2; ++rep) {
    const int sid   = rep * 256 + t;
    const int tt    = sid >> 8;
    const int rem   = sid & 255;
    const int i_rel = rem >> 6;
    const int ls    = rem & 63;
    const int i_    = (d0 >> 4) + i_rel;
    const int j     = i_ * 8 + (ls >> 3);
    const int s0    = (ls & 7) ^ (j & 7);
    const int dl    = 2 * (i_rel * 8 + (ls >> 3)) + (s0 >> 2);
    const int nl0   = tt * 32 + (s0 & 3) * 8;
    u16x8 o;
    #pragma unroll
    for (int jj = 0; jj < 8; ++jj) o[jj] = Ls[nl0 + jj][dl];
    const int tile = blockIdx.x * 2 + tt;
    *(u16x8*)&Vbt[((size_t)z * 64 + tile) * 4096 + i_ * 512 + ls * 8] = o;
  }
}

// per-wave quarter staging: 4 gload16 of the 16 per tile
#define ISSUE_K4(dst, kv0, part) do { \
  _Pragma("unroll") for (int i_ = 0; i_ < 4; ++i_) { int ii_ = (part)*4 + i_; \
    gload16(kgb + (((size_t)(kv0) + ii_ * 4 + (l >> 4)) << 7) + ((l & 15) << 3), (dst) + ii_ * 512); } \
  __builtin_amdgcn_sched_barrier(0); } while (0)

#define ISSUE_V4(dst, kv0, part) do { \
  _Pragma("unroll") for (int i_ = 0; i_ < 4; ++i_) { int ii_ = (part)*4 + i_; \
    gload16(vgb + ((size_t)((kv0) >> 5)) * 4096 + ii_ * 512 + l * 8, (dst) + ii_ * 512); } \
  __builtin_amdgcn_sched_barrier(0); } while (0)

#define WAIT_VM(n) do { asm volatile("s_waitcnt vmcnt(" #n ")" ::: "memory"); \
  __builtin_amdgcn_sched_barrier(0); } while (0)
#define WAIT_VM0 do { asm volatile("s_waitcnt vmcnt(0)" ::: "memory"); \
  __builtin_amdgcn_sched_barrier(0); } while (0)

// ---- fused diff-attention: 128-q blocks, 4 waves (head x q-group-pair),
//      full-kv sweep per wave, 4-slot ring (3 tiles prefetch), no-max softmax ----
__global__ __launch_bounds__(256, 2) void attn9_kernel(
    const u16* __restrict__ Qb, const u16* __restrict__ Kb, const u16* __restrict__ Vbt,
    const float* __restrict__ lq1, const float* __restrict__ lk1,
    const float* __restrict__ lq2, const float* __restrict__ lk2,
    const float* __restrict__ norm_w, u16* __restrict__ Xb)
{
  __shared__ __align__(16) u16 smem[32768];   // 64KB: 4-slot ring of (K 8KB | V 8KB); reused as xch

  const int tid = threadIdx.x;
  const int w   = tid >> 6;
  const int l   = tid & 63;
  const int hi  = l >> 5;
  const int q   = l & 31;
  const int h   = w >> 1;       // head within pair
  const int qg  = w & 1;        // q-group pair (64 q each)

  const int bid0 = blockIdx.x;
  const int bid = (bid0 & 7) * 32 + (bid0 >> 3);   // XCD swizzle (256 % 8 == 0)
  const int qt = bid & 15;
  const int he = (bid >> 4) & 3;
  const int b  = bid >> 6;
  const int q0 = qt * 128;
  const int bhe = b * 4 + he;

  // lambda (per wave)
  float lp1 = lq1[l] * lk1[l], lp2 = lq2[l] * lk2[l];
  #pragma unroll
  for (int off = 32; off; off >>= 1) { lp1 += __shfl_xor(lp1, off); lp2 += __shfl_xor(lp2, off); }
  const float lam = __expf(lp1) - __expf(lp2) + LAMBDA_INIT;
  asm volatile("" :: "v"(lam));

  // Q fragments for OWN head, two q-groups (qg*64 + g*32 + q)
  bf16x8 qf[2][4];
  #pragma unroll
  for (int g = 0; g < 2; ++g) {
    const u16* qp = Qb + ((size_t)(b * NN) + q0 + qg * 64 + g * 32 + q) * DD + he * 128 + h * 64 + hi * 8;
    #pragma unroll
    for (int dk = 0; dk < 4; ++dk)
      qf[g][dk] = *(const bf16x8*)(qp + dk * 16);
  }
  WAIT_VM0;       // drain lambda+Q loads before counted pipeline
  #pragma unroll
  for (int g = 0; g < 2; ++g)
    #pragma unroll
    for (int dk = 0; dk < 4; ++dk)
      asm volatile("" :: "v"(qf[g][dk]));

  const u16* kgb = Kb + (size_t)bhe * NN * 128;
  const u16* vgb = Vbt + (size_t)bhe * 64 * 4096;

  // prologue: stage tiles 0,1,2 into ring slots 0,1,2 (12 loads/wave)
  #pragma unroll
  for (int pt = 0; pt < 3; ++pt) {
    u16* slot = smem + pt * 8192;
    if (h == 0) ISSUE_K4(slot, pt * 32, qg);
    else        ISSUE_V4(slot + 4096, pt * 32, qg);
  }

  f32x16 O[2][4];
  #pragma unroll
  for (int g = 0; g < 2; ++g)
    #pragma unroll
    for (int dt = 0; dt < 4; ++dt) O[g][dt] = fz16();
  float sl[2] = {0.f, 0.f};

  const int jq  = (q >> 1) & 7;
  const int dq1 = (q & 1) << 2;

  for (int tt = 0; tt < 64; ++tt) {
    WAIT_VM(8);                         // own tile-tt loads (oldest 4) landed
    __builtin_amdgcn_s_barrier();       // all waves' tile-tt loads landed
    __builtin_amdgcn_sched_barrier(0);

    {
      const int nt = (tt + 3) & 63;     // wrap-dummy at tail keeps counts constant
      u16* slot = smem + ((tt + 3) & 3) * 8192;
      if (h == 0) ISSUE_K4(slot, nt * 32, qg);
      else        ISSUE_V4(slot + 4096, nt * 32, qg);
    }

    const u16* Kcur = smem + (tt & 3) * 8192;
    const u16* Vcur = Kcur + 4096;

    // ---- QK^T: S^T[kv][q] for own head; each K read feeds both q-groups ----
    f32x16 Sg[2];
    __builtin_amdgcn_s_setprio(1);
    {
      f32x16 a0 = fz16(), a1 = fz16();
      #pragma unroll
      for (int dk = 0; dk < 4; ++dk) {
        const int gd = h * 8 + dk * 2 + hi;
        const int g2 = (gd & 8) | ((gd & 7) ^ (q & 7));
        bf16x8 kf = *(const bf16x8*)&Kcur[q * 128 + g2 * 8];
        a0 = __builtin_amdgcn_mfma_f32_32x32x16_bf16(kf, qf[0][dk], a0, 0, 0, 0);
        a1 = __builtin_amdgcn_mfma_f32_32x32x16_bf16(kf, qf[1][dk], a1, 0, 0, 0);
      }
      Sg[0] = a0; Sg[1] = a1;
    }
    __builtin_amdgcn_s_setprio(0);

    // ---- no-max softmax per q-group: P = exp2(S), partial sums, permlane pack ----
    bf16x8 pb[2][2];
    #pragma unroll
    for (int g = 0; g < 2; ++g) {
      #pragma unroll
      for (int r = 0; r < 16; ++r)
        Sg[g][r] = __builtin_amdgcn_exp2f(Sg[g][r]);
      {
        float y0 = (Sg[g][0]  + Sg[g][1])  + (Sg[g][2]  + Sg[g][3]);
        float y1 = (Sg[g][4]  + Sg[g][5])  + (Sg[g][6]  + Sg[g][7]);
        float y2 = (Sg[g][8]  + Sg[g][9])  + (Sg[g][10] + Sg[g][11]);
        float y3 = (Sg[g][12] + Sg[g][13]) + (Sg[g][14] + Sg[g][15]);
        sl[g] += (y0 + y1) + (y2 + y3);
      }
      unsigned PK[8];
      #pragma unroll
      for (int p2 = 0; p2 < 8; ++p2)
        asm("v_cvt_pk_bf16_f32 %0, %1, %2" : "=v"(PK[p2]) : "v"(Sg[g][2*p2]), "v"(Sg[g][2*p2+1]));
      #pragma unroll
      for (int kb = 0; kb < 2; ++kb) {
        unsigned w0 = PK[4*kb + 0], w2v = PK[4*kb + 2];
        unsigned w1 = PK[4*kb + 1], w3v = PK[4*kb + 3];
        plswap(w0, w2v);
        plswap(w1, w3v);
        union { u32x4 u; bf16x8 v; } cv;
        cv.u = (u32x4){ w0, w1, w2v, w3v };
        pb[g][kb] = cv.v;
      }
    }

    // ---- PV: O^T[d][q] += V^T x P; each V read feeds both q-groups ----
    __builtin_amdgcn_s_setprio(1);
    #pragma unroll
    for (int kk = 0; kk < 2; ++kk)
      #pragma unroll
      for (int dt = 0; dt < 4; ++dt) {
        const int j = dt * 16 + (q >> 1);
        const int s8 = (dq1 + kk * 2 + hi) ^ jq;
        bf16x8 vf = *(const bf16x8*)&Vcur[j * 64 + s8 * 8];
        O[0][dt] = __builtin_amdgcn_mfma_f32_32x32x16_bf16(vf, pb[0][kk], O[0][dt], 0, 0, 0);
        O[1][dt] = __builtin_amdgcn_mfma_f32_32x32x16_bf16(vf, pb[1][kk], O[1][dt], 0, 0, 0);
      }
    __builtin_amdgcn_s_setprio(0);
  }

  WAIT_VM0;          // drain wrap-dummy prefetch before reusing LDS
  __syncthreads();

  // ---- L (full-row sum), cross-head diff, RMSNorm, store ----
  float L[2];
  #pragma unroll
  for (int g = 0; g < 2; ++g) L[g] = xhalf_add(sl[g]);

  float* xch = (float*)smem;           // 64KB = [d 128][q 128]
  if (h == 1) {
    #pragma unroll
    for (int g = 0; g < 2; ++g) {
      const float s2 = lam / L[g];
      #pragma unroll
      for (int dt = 0; dt < 4; ++dt)
        #pragma unroll
        for (int r = 0; r < 16; ++r) {
          const int crow = (r & 3) + 8 * (r >> 2) + 4 * hi;
          xch[(dt * 32 + crow) * 128 + qg * 64 + g * 32 + q] = O[g][dt][r] * s2;
        }
    }
  }
  __syncthreads();
  if (h == 0) {
    #pragma unroll
    for (int g = 0; g < 2; ++g) {
      const float i1 = 1.f / L[g];
      float ss = 0.f;
      #pragma unroll
      for (int dt = 0; dt < 4; ++dt)
        #pragma unroll
        for (int r = 0; r < 16; ++r) {
          const int crow = (r & 3) + 8 * (r >> 2) + 4 * hi;
          float o = O[g][dt][r] * i1 - xch[(dt * 32 + crow) * 128 + qg * 64 + g * 32 + q];
          O[g][dt][r] = o;
          ss += o * o;
        }
      ss = xhalf_add(ss);
      const float rstd = rsqrtf(ss * (1.f / 128.f) + EPSV);
      const size_t xo = ((size_t)(b * NN) + q0 + qg * 64 + g * 32 + q) * DD + he * 128;
      #pragma unroll
      for (int dt = 0; dt < 4; ++dt)
        #pragma unroll
        for (int rq = 0; rq < 4; ++rq) {
          const int d0 = dt * 32 + rq * 8 + hi * 4;
          const float4 nw = *(const float4*)&norm_w[d0];
          u16x4 ov;
          ov[0] = f2bf(O[g][dt][rq*4 + 0] * rstd * nw.x * 0.2f);
          ov[1] = f2bf(O[g][dt][rq*4 + 1] * rstd * nw.y * 0.2f);
          ov[2] = f2bf(O[g][dt][rq*4 + 2] * rstd * nw.z * 0.2f);
          ov[3] = f2bf(O[g][dt][rq*4 + 3] * rstd * nw.w * 0.2f);
          *(u16x4*)&Xb[xo + d0] = ov;
        }
    }
  }
}

// ---- projection: bf16 MFMA, 64x64 tile, double-buffered ----
#define PLOAD(k0) do { \
    _Pragma("unroll") for (int p_ = 0; p_ < 2; ++p_) { \
      int idx_ = p_*256 + t; int r_ = idx_ >> 3, gi_ = idx_ & 7; \
      ra[p_] = *(const u16x8*)&Xb[(size_t)(row0 + r_) * DD + (k0) + gi_*8]; \
      rb[p_] = *(const u16x8*)&Wb[(size_t)(col0 + r_) * DD + (k0) + gi_*8]; } \
  } while (0)
#define PWRITE(bi) do { \
    _Pragma("unroll") for (int p_ = 0; p_ < 2; ++p_) { \
      int idx_ = p_*256 + t; int r_ = idx_ >> 3, gi_ = idx_ & 7; \
      *(u16x8*)&As[bi][r_*64 + ((gi_ ^ (r_ & 7)) << 3)] = ra[p_]; \
      *(u16x8*)&Bs[bi][r_*64 + ((gi_ ^ (r_ & 7)) << 3)] = rb[p_]; } \
  } while (0)

__global__ __launch_bounds__(256, 2) void proj_mfma_kernel(
    const u16* __restrict__ Xb, const u16* __restrict__ Wb,
    const float* __restrict__ bias, float* __restrict__ out)
{
  __shared__ __align__(16) u16 As[2][64*64];
  __shared__ __align__(16) u16 Bs[2][64*64];
  const int t = threadIdx.x;
  const int w = t >> 6, l = t & 63, g = l >> 4, c = l & 15;
  const int wm = w >> 1, wn = w & 1;
  const int row0 = blockIdx.x * 64, col0 = blockIdx.y * 64;

  u16x8 ra[2], rb[2];
  f32x4 acc[2][2];
  #pragma unroll
  for (int i = 0; i < 2; ++i)
    #pragma unroll
    for (int j = 0; j < 2; ++j) acc[i][j] = (f32x4){0,0,0,0};
  float bj[2];
  #pragma unroll
  for (int j = 0; j < 2; ++j) bj[j] = bias[col0 + wn*32 + j*16 + c];

  PLOAD(0);
  PWRITE(0);
  __syncthreads();
  for (int s = 0; s < 8; ++s) {
    const int bi = s & 1;
    if (s < 7) PLOAD((s + 1) * 64);
    #pragma unroll
    for (int kc = 0; kc < 2; ++kc) {
      bf16x8 af[2], bfv[2];
      #pragma unroll
      for (int i = 0; i < 2; ++i) {
        int rowa = wm*32 + i*16 + c;
        af[i]  = *(const bf16x8*)&As[bi][rowa*64 + (((kc*4 + g) ^ (c & 7)) << 3)];
        int rowb = wn*32 + i*16 + c;
        bfv[i] = *(const bf16x8*)&Bs[bi][rowb*64 + (((kc*4 + g) ^ (c & 7)) << 3)];
      }
      #pragma unroll
      for (int i = 0; i < 2; ++i)
        #pragma unroll
        for (int j = 0; j < 2; ++j)
          acc[i][j] = __builtin_amdgcn_mfma_f32_16x16x32_bf16(af[i], bfv[j], acc[i][j], 0, 0, 0);
    }
    if (s < 7) PWRITE((s + 1) & 1);
    __syncthreads();
  }
  #pragma unroll
  for (int i = 0; i < 2; ++i)
    #pragma unroll
    for (int j = 0; j < 2; ++j)
      #pragma unroll
      for (int rr = 0; rr < 4; ++rr)
        out[(size_t)(row0 + wm*32 + i*16 + g*4 + rr) * DD + col0 + wn*32 + j*16 + c] = acc[i][j][rr] + bj[j];
}

extern "C" void kernel_launch(void* const* d_in, const int* in_sizes, int n_in,
                              void* d_out, int out_size, void* d_ws, size_t ws_size,
                              hipStream_t stream) {
    const float* q      = (const float*)d_in[0];
    const float* k      = (const float*)d_in[1];
    const float* v      = (const float*)d_in[2];
    const float* lq1    = (const float*)d_in[3];
    const float* lk1    = (const float*)d_in[4];
    const float* lq2    = (const float*)d_in[5];
    const float* lk2    = (const float*)d_in[6];
    const float* norm_w = (const float*)d_in[7];
    const float* out_w  = (const float*)d_in[8];
    const float* out_b  = (const float*)d_in[9];
    float* out = (float*)d_out;

    u16* Qb  = (u16*)d_ws;                                   // 8 MB
    u16* Kb  = (u16*)((char*)d_ws + (8u  << 20));            // 8 MB
    u16* Vbt = (u16*)((char*)d_ws + (16u << 20));            // 8 MB
    u16* Wb  = (u16*)((char*)d_ws + (24u << 20));            // 0.5 MB
    u16* Xb  = (u16*)((char*)d_ws + (25u << 20));            // 8 MB

    prep_kernel<<<BB * NN + 256, 256, 0, stream>>>(q, k, out_w, Qb, Kb, Wb);
    v_prep_kernel<<<dim3(32, 2, 16), 256, 0, stream>>>(v, Vbt);
    attn9_kernel<<<256, 256, 0, stream>>>(Qb, Kb, Vbt, lq1, lk1, lq2, lk2, norm_w, Xb);
    proj_mfma_kernel<<<dim3(128, 8), 256, 0, stream>>>(Xb, Wb, out_b, out);
}

// Round 14
// 88.492 us; speedup vs baseline: 1.1197x; 1.1197x over previous
//
#include <hip/hip_runtime.h>
#include <math.h>

#define BB 4
#define NN 2048
#define DD 512
#define LAMBDA_INIT 0.8f
#define EPSV 1e-5f

typedef __attribute__((ext_vector_type(8))) short bf16x8;
typedef __attribute__((ext_vector_type(4))) float f32x4;
typedef __attribute__((ext_vector_type(16))) float f32x16;
typedef unsigned short u16;
typedef __attribute__((ext_vector_type(4))) u16 u16x4;
typedef __attribute__((ext_vector_type(8))) u16 u16x8;
typedef __attribute__((ext_vector_type(4))) unsigned u32x4;

__device__ __forceinline__ u16 f2bf(float f) {
  unsigned u = __builtin_bit_cast(unsigned, f);
  u = (u + 0x7FFFu + ((u >> 16) & 1u)) >> 16;
  return (u16)u;
}

__device__ __forceinline__ void gload16(const void* g, void* l) {
  __builtin_amdgcn_global_load_lds((const __attribute__((address_space(1))) unsigned*)g,
                                   (__attribute__((address_space(3))) unsigned*)l, 16, 0, 0);
}

__device__ __forceinline__ f32x16 fz16() {
  f32x16 z;
  #pragma unroll
  for (int i = 0; i < 16; ++i) z[i] = 0.f;
  return z;
}

__device__ __forceinline__ void plswap(unsigned &a, unsigned &b) {
  asm("v_permlane32_swap_b32 %0, %1" : "+v"(a), "+v"(b));
}
// cross-half add; MUST be called with full wave exec (permlane FI semantics)
__device__ __forceinline__ float xhalf_add(float x) {
  unsigned a = __builtin_bit_cast(unsigned, x), b;
  asm("v_mov_b32 %0, %1" : "=v"(b) : "v"(a));
  asm("v_permlane32_swap_b32 %0, %1" : "+v"(a), "+v"(b));
  return __builtin_bit_cast(float, a) + __builtin_bit_cast(float, b);
}

// ---- prepass: Q bf16 (scaled 0.125*log2e), K bf16 pre-swizzled rows, W bf16 ----
__global__ __launch_bounds__(256) void prep_kernel(
    const float* __restrict__ q, const float* __restrict__ k, const float* __restrict__ w,
    u16* __restrict__ Qb, u16* __restrict__ Kb, u16* __restrict__ Wb)
{
  const int t = threadIdx.x;
  const int bid = blockIdx.x;
  if (bid >= BB * NN) {
    const size_t idx = (size_t)(bid - BB * NN) * 256 + t;
    float4 f = *(const float4*)&w[idx * 4];
    u16x4 o = { f2bf(f.x), f2bf(f.y), f2bf(f.z), f2bf(f.w) };
    *(u16x4*)&Wb[idx * 4] = o;
    return;
  }
  const size_t row = bid;
  const int n = bid & (NN - 1);
  const int b = bid >> 11;
  if (t < 128) {
    const float s = 0.125f * 1.4426950408889634f;
    float4 f = *(const float4*)&q[row * DD + t * 4];
    u16x4 o = { f2bf(f.x * s), f2bf(f.y * s), f2bf(f.z * s), f2bf(f.w * s) };
    *(u16x4*)&Qb[row * DD + t * 4] = o;
  } else {
    const int f0 = (t - 128) * 4;
    float4 f = *(const float4*)&k[row * DD + f0];
    const int he = f0 >> 7, fi = f0 & 127;
    const int gi = fi >> 3, lo = fi & 7;
    const int gi2 = (gi & 8) | ((gi & 7) ^ (n & 7));
    u16x4 o = { f2bf(f.x), f2bf(f.y), f2bf(f.z), f2bf(f.w) };
    *(u16x4*)&Kb[((size_t)(b * 4 + he) * NN + n) * 128 + gi2 * 8 + lo] = o;
  }
}

// ---- prepass: V tile-image (8KB per 32-kv tile, staged linearly) ----
__global__ __launch_bounds__(256) void v_prep_kernel(const float* __restrict__ v, u16* __restrict__ Vbt) {
  __shared__ u16 Ls[64][72];
  const int t = threadIdx.x;
  const int n0 = blockIdx.x * 64;
  const int d0 = blockIdx.y * 64;
  const int z  = blockIdx.z;             // b*4+he
  #pragma unroll
  for (int p = 0; p < 4; ++p) {
    int n = p * 16 + (t >> 4), f4 = t & 15;
    float4 rv = *(const float4*)&v[((size_t)((z >> 2) * NN + n0 + n)) * DD + (z & 3) * 128 + d0 + f4 * 4];
    Ls[n][f4*4+0] = f2bf(rv.x); Ls[n][f4*4+1] = f2bf(rv.y);
    Ls[n][f4*4+2] = f2bf(rv.z); Ls[n][f4*4+3] = f2bf(rv.w);
  }
  __syncthreads();
  #pragma unroll
  for (int rep = 0; rep < 2; ++rep) {
    const int sid   = rep * 256 + t;
    const int tt    = sid >> 8;
    const int rem   = sid & 255;
    const int i_rel = rem >> 6;
    const int ls    = rem & 63;
    const int i_    = (d0 >> 4) + i_rel;
    const int j     = i_ * 8 + (ls >> 3);
    const int s0    = (ls & 7) ^ (j & 7);
    const int dl    = 2 * (i_rel * 8 + (ls >> 3)) + (s0 >> 2);
    const int nl0   = tt * 32 + (s0 & 3) * 8;
    u16x8 o;
    #pragma unroll
    for (int jj = 0; jj < 8; ++jj) o[jj] = Ls[nl0 + jj][dl];
    const int tile = blockIdx.x * 2 + tt;
    *(u16x8*)&Vbt[((size_t)z * 64 + tile) * 4096 + i_ * 512 + ls * 8] = o;
  }
}

#define ISSUE_K(dst, kv0) do { \
  _Pragma("unroll") for (int i_ = 0; i_ < 8; ++i_) \
    gload16(kgb + (((size_t)(kv0) + i_ * 4 + (l >> 4)) << 7) + ((l & 15) << 3), (dst) + i_ * 512); \
  __builtin_amdgcn_sched_barrier(0); } while (0)

#define ISSUE_V(dst, kv0) do { \
  _Pragma("unroll") for (int i_ = 0; i_ < 8; ++i_) \
    gload16(vgb + ((size_t)((kv0) >> 5)) * 4096 + i_ * 512 + l * 8, (dst) + i_ * 512); \
  __builtin_amdgcn_sched_barrier(0); } while (0)

#define WAIT_VM0 do { asm volatile("s_waitcnt vmcnt(0)" ::: "memory"); \
  __builtin_amdgcn_sched_barrier(0); } while (0)

// ---- fused diff-attention: 4 waves (qh x kvh), shared staged tiles, raw s_barrier
//      + per-wave counted vmcnt, NO-MAX softmax (P=exp2(S)), hw exp2, permlane pack ----
__global__ __launch_bounds__(256, 2) void attn10_kernel(
    const u16* __restrict__ Qb, const u16* __restrict__ Kb, const u16* __restrict__ Vbt,
    const float* __restrict__ lq1, const float* __restrict__ lk1,
    const float* __restrict__ lq2, const float* __restrict__ lk2,
    const float* __restrict__ norm_w, u16* __restrict__ Xb)
{
  __shared__ __align__(16) u16 smem[32768];        // K dbuf 32KB + V dbuf 32KB (aliased by merge)
  __shared__ float stats[2][2][2][32];             // [qh][kvh][h][q] = L partial

  u16* KB = smem;              // [(kvh*2+db)*4096]
  u16* VB = smem + 16384;

  const int tid = threadIdx.x;
  const int w   = tid >> 6;
  const int l   = tid & 63;
  const int hi  = l >> 5;
  const int q   = l & 31;
  const int kvh = w & 1;
  const int qh  = w >> 1;

  const int bid0 = blockIdx.x;
  const int bid = (bid0 & 7) * 64 + (bid0 >> 3);   // XCD swizzle (512 % 8 == 0)
  const int qt = bid & 31;
  const int he = (bid >> 5) & 3;
  const int b  = bid >> 7;
  const int q0 = qt * 64;
  const int bhe = b * 4 + he;
  const int qrow = q0 + qh * 32 + q;

  // lambda (per wave)
  float lp1 = lq1[l] * lk1[l], lp2 = lq2[l] * lk2[l];
  #pragma unroll
  for (int off = 32; off; off >>= 1) { lp1 += __shfl_xor(lp1, off); lp2 += __shfl_xor(lp2, off); }
  const float lam = __expf(lp1) - __expf(lp2) + LAMBDA_INIT;
  asm volatile("" :: "v"(lam));

  // Q fragments: B-operand (32x32x16): col=q, k = hi*8+j
  bf16x8 qf[2][4];
  {
    const u16* qp = Qb + ((size_t)(b * NN) + qrow) * DD + he * 128 + hi * 8;
    #pragma unroll
    for (int h = 0; h < 2; ++h)
      #pragma unroll
      for (int dk = 0; dk < 4; ++dk)
        qf[h][dk] = *(const bf16x8*)(qp + h * 64 + dk * 16);
  }
  WAIT_VM0;       // drain lambda+Q loads before counted pipeline
  #pragma unroll
  for (int h = 0; h < 2; ++h)
    #pragma unroll
    for (int dk = 0; dk < 4; ++dk)
      asm volatile("" :: "v"(qf[h][dk]));

  const u16* kgb = Kb + (size_t)bhe * NN * 128;
  const u16* vgb = Vbt + (size_t)bhe * 64 * 4096;
  const int kvb = kvh * 1024;

  if (qh == 0) ISSUE_K(&KB[kvh * 8192], kvb);
  else         ISSUE_V(&VB[kvh * 8192], kvb);

  f32x16 O[2][4];
  #pragma unroll
  for (int h = 0; h < 2; ++h)
    #pragma unroll
    for (int dt = 0; dt < 4; ++dt) O[h][dt] = fz16();
  float sl[2] = {0.f, 0.f};

  const int jq  = (q >> 1) & 7;
  const int dq1 = (q & 1) << 2;

  for (int tt = 0; tt < 32; ++tt) {
    WAIT_VM0;                           // own stream for tile tt landed
    __builtin_amdgcn_s_barrier();       // partner's stream landed too
    __builtin_amdgcn_sched_barrier(0);

    if (tt != 31) {
      const int kvn = kvb + (tt + 1) * 32;
      const int db = (tt + 1) & 1;
      if (qh == 0) ISSUE_K(&KB[(kvh * 2 + db) * 4096], kvn);
      else         ISSUE_V(&VB[(kvh * 2 + db) * 4096], kvn);
    }

    const u16* Kcur = &KB[(kvh * 2 + (tt & 1)) * 4096];
    const u16* Vcur = &VB[(kvh * 2 + (tt & 1)) * 4096];

    // ---- QK^T: S^T[kv][q], A=K LDS, B=Q regs ----
    f32x16 S[2];
    __builtin_amdgcn_s_setprio(1);
    #pragma unroll
    for (int h = 0; h < 2; ++h) {
      f32x16 acc = fz16();
      #pragma unroll
      for (int dk = 0; dk < 4; ++dk) {
        const int gd = h * 8 + dk * 2 + hi;
        const int g2 = (gd & 8) | ((gd & 7) ^ (q & 7));
        bf16x8 kf = *(const bf16x8*)&Kcur[q * 128 + g2 * 8];
        acc = __builtin_amdgcn_mfma_f32_32x32x16_bf16(kf, qf[h][dk], acc, 0, 0, 0);
      }
      S[h] = acc;
    }
    __builtin_amdgcn_s_setprio(0);

    // ---- no-max softmax: P = exp2(S) directly; tree-sum partial L; permlane pack ----
    bf16x8 pb[2][2];
    #pragma unroll
    for (int h = 0; h < 2; ++h) {
      #pragma unroll
      for (int r = 0; r < 16; ++r)
        S[h][r] = __builtin_amdgcn_exp2f(S[h][r]);
      float y0 = (S[h][0]  + S[h][1])  + (S[h][2]  + S[h][3]);
      float y1 = (S[h][4]  + S[h][5])  + (S[h][6]  + S[h][7]);
      float y2 = (S[h][8]  + S[h][9])  + (S[h][10] + S[h][11]);
      float y3 = (S[h][12] + S[h][13]) + (S[h][14] + S[h][15]);
      sl[h] += (y0 + y1) + (y2 + y3);

      unsigned PK[8];
      #pragma unroll
      for (int p2 = 0; p2 < 8; ++p2)
        asm("v_cvt_pk_bf16_f32 %0, %1, %2" : "=v"(PK[p2]) : "v"(S[h][2*p2]), "v"(S[h][2*p2+1]));
      #pragma unroll
      for (int kb = 0; kb < 2; ++kb) {
        unsigned w0 = PK[4*kb + 0], w2v = PK[4*kb + 2];
        unsigned w1 = PK[4*kb + 1], w3v = PK[4*kb + 3];
        plswap(w0, w2v);
        plswap(w1, w3v);
        union { u32x4 u; bf16x8 v; } cv;
        cv.u = (u32x4){ w0, w1, w2v, w3v };
        pb[h][kb] = cv.v;
      }
    }

    // ---- PV: O^T[d][q] += V^T x P ----
    __builtin_amdgcn_s_setprio(1);
    #pragma unroll
    for (int kk = 0; kk < 2; ++kk)
      #pragma unroll
      for (int dt = 0; dt < 4; ++dt) {
        const int j = dt * 16 + (q >> 1);
        const int s8 = (dq1 + kk * 2 + hi) ^ jq;
        bf16x8 vf = *(const bf16x8*)&Vcur[j * 64 + s8 * 8];
        O[0][dt] = __builtin_amdgcn_mfma_f32_32x32x16_bf16(vf, pb[0][kk], O[0][dt], 0, 0, 0);
        O[1][dt] = __builtin_amdgcn_mfma_f32_32x32x16_bf16(vf, pb[1][kk], O[1][dt], 0, 0, 0);
      }
    __builtin_amdgcn_s_setprio(0);
  }

  // ---- cross-kv-half merge: plain sums (no max basis) ----
  // xhalf_add MUST run with full wave exec (permlane reads from all lanes)
  const float slr0 = xhalf_add(sl[0]);
  const float slr1 = xhalf_add(sl[1]);
  __syncthreads();
  if (hi == 0) {
    stats[qh][kvh][0][q] = slr0;
    stats[qh][kvh][1][q] = slr1;
  }
  __syncthreads();
  float L[2];
  #pragma unroll
  for (int h = 0; h < 2; ++h)
    L[h] = stats[qh][0][h][q] + stats[qh][1][h][q];

  float* xch = (float*)smem;           // 64KB, staging buffers dead now
  __syncthreads();
  if (kvh == 1) {
    #pragma unroll
    for (int h = 0; h < 2; ++h)
      #pragma unroll
      for (int dt = 0; dt < 4; ++dt)
        #pragma unroll
        for (int r = 0; r < 16; ++r)
          xch[qh * 8192 + ((h * 4 + dt) * 16 + r) * 64 + l] = O[h][dt][r];
  }
  __syncthreads();
  if (kvh == 0) {
    #pragma unroll
    for (int h = 0; h < 2; ++h)
      #pragma unroll
      for (int dt = 0; dt < 4; ++dt)
        #pragma unroll
        for (int r = 0; r < 16; ++r)
          O[h][dt][r] += xch[qh * 8192 + ((h * 4 + dt) * 16 + r) * 64 + l];

    // ---- epilogue: diff, RMSNorm over d, store X bf16 ----
    const float i1 = 1.f / L[0];
    const float i2 = lam / L[1];
    float ss = 0.f;
    f32x16 od[4];
    #pragma unroll
    for (int dt = 0; dt < 4; ++dt)
      #pragma unroll
      for (int r = 0; r < 16; ++r) {
        float o = O[0][dt][r] * i1 - O[1][dt][r] * i2;
        od[dt][r] = o; ss += o * o;
      }
    // rows live per (q,hi): own 64 d-values + partner-half 64 -> cross-half add ONLY
    ss += __shfl_xor(ss, 32);
    const float rstd = rsqrtf(ss * (1.f / 128.f) + EPSV);
    const size_t xo = ((size_t)(b * NN) + qrow) * DD + he * 128;
    #pragma unroll
    for (int dt = 0; dt < 4; ++dt)
      #pragma unroll
      for (int rq = 0; rq < 4; ++rq) {
        const int d0 = dt * 32 + rq * 8 + hi * 4;
        const float4 nw = *(const float4*)&norm_w[d0];
        u16x4 ov;
        ov[0] = f2bf(od[dt][rq*4 + 0] * rstd * nw.x * 0.2f);
        ov[1] = f2bf(od[dt][rq*4 + 1] * rstd * nw.y * 0.2f);
        ov[2] = f2bf(od[dt][rq*4 + 2] * rstd * nw.z * 0.2f);
        ov[3] = f2bf(od[dt][rq*4 + 3] * rstd * nw.w * 0.2f);
        *(u16x4*)&Xb[xo + d0] = ov;
      }
  }
}

// ---- projection: bf16 MFMA, 64x64 tile, double-buffered ----
#define PLOAD(k0) do { \
    _Pragma("unroll") for (int p_ = 0; p_ < 2; ++p_) { \
      int idx_ = p_*256 + t; int r_ = idx_ >> 3, gi_ = idx_ & 7; \
      ra[p_] = *(const u16x8*)&Xb[(size_t)(row0 + r_) * DD + (k0) + gi_*8]; \
      rb[p_] = *(const u16x8*)&Wb[(size_t)(col0 + r_) * DD + (k0) + gi_*8]; } \
  } while (0)
#define PWRITE(bi) do { \
    _Pragma("unroll") for (int p_ = 0; p_ < 2; ++p_) { \
      int idx_ = p_*256 + t; int r_ = idx_ >> 3, gi_ = idx_ & 7; \
      *(u16x8*)&As[bi][r_*64 + ((gi_ ^ (r_ & 7)) << 3)] = ra[p_]; \
      *(u16x8*)&Bs[bi][r_*64 + ((gi_ ^ (r_ & 7)) << 3)] = rb[p_]; } \
  } while (0)

__global__ __launch_bounds__(256, 2) void proj_mfma_kernel(
    const u16* __restrict__ Xb, const u16* __restrict__ Wb,
    const float* __restrict__ bias, float* __restrict__ out)
{
  __shared__ __align__(16) u16 As[2][64*64];
  __shared__ __align__(16) u16 Bs[2][64*64];
  const int t = threadIdx.x;
  const int w = t >> 6, l = t & 63, g = l >> 4, c = l & 15;
  const int wm = w >> 1, wn = w & 1;
  const int row0 = blockIdx.x * 64, col0 = blockIdx.y * 64;

  u16x8 ra[2], rb[2];
  f32x4 acc[2][2];
  #pragma unroll
  for (int i = 0; i < 2; ++i)
    #pragma unroll
    for (int j = 0; j < 2; ++j) acc[i][j] = (f32x4){0,0,0,0};
  float bj[2];
  #pragma unroll
  for (int j = 0; j < 2; ++j) bj[j] = bias[col0 + wn*32 + j*16 + c];

  PLOAD(0);
  PWRITE(0);
  __syncthreads();
  for (int s = 0; s < 8; ++s) {
    const int bi = s & 1;
    if (s < 7) PLOAD((s + 1) * 64);
    #pragma unroll
    for (int kc = 0; kc < 2; ++kc) {
      bf16x8 af[2], bfv[2];
      #pragma unroll
      for (int i = 0; i < 2; ++i) {
        int rowa = wm*32 + i*16 + c;
        af[i]  = *(const bf16x8*)&As[bi][rowa*64 + (((kc*4 + g) ^ (c & 7)) << 3)];
        int rowb = wn*32 + i*16 + c;
        bfv[i] = *(const bf16x8*)&Bs[bi][rowb*64 + (((kc*4 + g) ^ (c & 7)) << 3)];
      }
      #pragma unroll
      for (int i = 0; i < 2; ++i)
        #pragma unroll
        for (int j = 0; j < 2; ++j)
          acc[i][j] = __builtin_amdgcn_mfma_f32_16x16x32_bf16(af[i], bfv[j], acc[i][j], 0, 0, 0);
    }
    if (s < 7) PWRITE((s + 1) & 1);
    __syncthreads();
  }
  #pragma unroll
  for (int i = 0; i < 2; ++i)
    #pragma unroll
    for (int j = 0; j < 2; ++j)
      #pragma unroll
      for (int rr = 0; rr < 4; ++rr)
        out[(size_t)(row0 + wm*32 + i*16 + g*4 + rr) * DD + col0 + wn*32 + j*16 + c] = acc[i][j][rr] + bj[j];
}

extern "C" void kernel_launch(void* const* d_in, const int* in_sizes, int n_in,
                              void* d_out, int out_size, void* d_ws, size_t ws_size,
                              hipStream_t stream) {
    const float* q      = (const float*)d_in[0];
    const float* k      = (const float*)d_in[1];
    const float* v      = (const float*)d_in[2];
    const float* lq1    = (const float*)d_in[3];
    const float* lk1    = (const float*)d_in[4];
    const float* lq2    = (const float*)d_in[5];
    const float* lk2    = (const float*)d_in[6];
    const float* norm_w = (const float*)d_in[7];
    const float* out_w  = (const float*)d_in[8];
    const float* out_b  = (const float*)d_in[9];
    float* out = (float*)d_out;

    u16* Qb  = (u16*)d_ws;                                   // 8 MB
    u16* Kb  = (u16*)((char*)d_ws + (8u  << 20));            // 8 MB
    u16* Vbt = (u16*)((char*)d_ws + (16u << 20));            // 8 MB
    u16* Wb  = (u16*)((char*)d_ws + (24u << 20));            // 0.5 MB
    u16* Xb  = (u16*)((char*)d_ws + (25u << 20));            // 8 MB

    prep_kernel<<<BB * NN + 256, 256, 0, stream>>>(q, k, out_w, Qb, Kb, Wb);
    v_prep_kernel<<<dim3(32, 2, 16), 256, 0, stream>>>(v, Vbt);
    attn10_kernel<<<512, 256, 0, stream>>>(Qb, Kb, Vbt, lq1, lk1, lq2, lk2, norm_w, Xb);
    proj_mfma_kernel<<<dim3(128, 8), 256, 0, stream>>>(Xb, Wb, out_b, out);
}

// Round 15
// 86.867 us; speedup vs baseline: 1.1406x; 1.0187x over previous
//
#include <hip/hip_runtime.h>
#include <math.h>

#define BB 4
#define NN 2048
#define DD 512
#define LAMBDA_INIT 0.8f
#define EPSV 1e-5f

typedef __attribute__((ext_vector_type(8))) short bf16x8;
typedef __attribute__((ext_vector_type(4))) float f32x4;
typedef __attribute__((ext_vector_type(16))) float f32x16;
typedef unsigned short u16;
typedef __attribute__((ext_vector_type(4))) u16 u16x4;
typedef __attribute__((ext_vector_type(8))) u16 u16x8;
typedef __attribute__((ext_vector_type(4))) unsigned u32x4;

__device__ __forceinline__ u16 f2bf(float f) {
  unsigned u = __builtin_bit_cast(unsigned, f);
  u = (u + 0x7FFFu + ((u >> 16) & 1u)) >> 16;
  return (u16)u;
}

__device__ __forceinline__ void gload16(const void* g, void* l) {
  __builtin_amdgcn_global_load_lds((const __attribute__((address_space(1))) unsigned*)g,
                                   (__attribute__((address_space(3))) unsigned*)l, 16, 0, 0);
}

__device__ __forceinline__ f32x16 fz16() {
  f32x16 z;
  #pragma unroll
  for (int i = 0; i < 16; ++i) z[i] = 0.f;
  return z;
}

__device__ __forceinline__ void plswap(unsigned &a, unsigned &b) {
  asm("v_permlane32_swap_b32 %0, %1" : "+v"(a), "+v"(b));
}
// cross-half add; MUST be called with full wave exec
__device__ __forceinline__ float xhalf_add(float x) {
  unsigned a = __builtin_bit_cast(unsigned, x), b;
  asm("v_mov_b32 %0, %1" : "=v"(b) : "v"(a));
  asm("v_permlane32_swap_b32 %0, %1" : "+v"(a), "+v"(b));
  return __builtin_bit_cast(float, a) + __builtin_bit_cast(float, b);
}

// ---- prepass: Q bf16 (scaled 0.125*log2e), K bf16 pre-swizzled rows, W bf16 ----
__global__ __launch_bounds__(256) void prep_kernel(
    const float* __restrict__ q, const float* __restrict__ k, const float* __restrict__ w,
    u16* __restrict__ Qb, u16* __restrict__ Kb, u16* __restrict__ Wb)
{
  const int t = threadIdx.x;
  const int bid = blockIdx.x;
  if (bid >= BB * NN) {
    const size_t idx = (size_t)(bid - BB * NN) * 256 + t;
    float4 f = *(const float4*)&w[idx * 4];
    u16x4 o = { f2bf(f.x), f2bf(f.y), f2bf(f.z), f2bf(f.w) };
    *(u16x4*)&Wb[idx * 4] = o;
    return;
  }
  const size_t row = bid;
  const int n = bid & (NN - 1);
  const int b = bid >> 11;
  if (t < 128) {
    const float s = 0.125f * 1.4426950408889634f;
    float4 f = *(const float4*)&q[row * DD + t * 4];
    u16x4 o = { f2bf(f.x * s), f2bf(f.y * s), f2bf(f.z * s), f2bf(f.w * s) };
    *(u16x4*)&Qb[row * DD + t * 4] = o;
  } else {
    const int f0 = (t - 128) * 4;
    float4 f = *(const float4*)&k[row * DD + f0];
    const int he = f0 >> 7, fi = f0 & 127;
    const int gi = fi >> 3, lo = fi & 7;
    const int gi2 = (gi & 8) | ((gi & 7) ^ (n & 7));
    u16x4 o = { f2bf(f.x), f2bf(f.y), f2bf(f.z), f2bf(f.w) };
    *(u16x4*)&Kb[((size_t)(b * 4 + he) * NN + n) * 128 + gi2 * 8 + lo] = o;
  }
}

// ---- prepass: V tile-image (8KB per 32-kv tile, staged linearly) ----
__global__ __launch_bounds__(256) void v_prep_kernel(const float* __restrict__ v, u16* __restrict__ Vbt) {
  __shared__ u16 Ls[64][72];
  const int t = threadIdx.x;
  const int n0 = blockIdx.x * 64;
  const int d0 = blockIdx.y * 64;
  const int z  = blockIdx.z;             // b*4+he
  #pragma unroll
  for (int p = 0; p < 4; ++p) {
    int n = p * 16 + (t >> 4), f4 = t & 15;
    float4 rv = *(const float4*)&v[((size_t)((z >> 2) * NN + n0 + n)) * DD + (z & 3) * 128 + d0 + f4 * 4];
    Ls[n][f4*4+0] = f2bf(rv.x); Ls[n][f4*4+1] = f2bf(rv.y);
    Ls[n][f4*4+2] = f2bf(rv.z); Ls[n][f4*4+3] = f2bf(rv.w);
  }
  __syncthreads();
  #pragma unroll
  for (int rep = 0; rep < 2; ++rep) {
    const int sid   = rep * 256 + t;
    const int tt    = sid >> 8;
    const int rem   = sid & 255;
    const int i_rel = rem >> 6;
    const int ls    = rem & 63;
    const int i_    = (d0 >> 4) + i_rel;
    const int j     = i_ * 8 + (ls >> 3);
    const int s0    = (ls & 7) ^ (j & 7);
    const int dl    = 2 * (i_rel * 8 + (ls >> 3)) + (s0 >> 2);
    const int nl0   = tt * 32 + (s0 & 3) * 8;
    u16x8 o;
    #pragma unroll
    for (int jj = 0; jj < 8; ++jj) o[jj] = Ls[nl0 + jj][dl];
    const int tile = blockIdx.x * 2 + tt;
    *(u16x8*)&Vbt[((size_t)z * 64 + tile) * 4096 + i_ * 512 + ls * 8] = o;
  }
}

// quarter-jobs: 4 gload16 of the 8 per (stream, tile); half selects which 4
#define ISSUE_K4(dst, kv0, half) do { \
  _Pragma("unroll") for (int i_ = 0; i_ < 4; ++i_) { int ii_ = (half)*4 + i_; \
    gload16(kgb + (((size_t)(kv0) + ii_ * 4 + (l >> 4)) << 7) + ((l & 15) << 3), (dst) + ii_ * 512); } \
  __builtin_amdgcn_sched_barrier(0); } while (0)

#define ISSUE_V4(dst, kv0, half) do { \
  _Pragma("unroll") for (int i_ = 0; i_ < 4; ++i_) { int ii_ = (half)*4 + i_; \
    gload16(vgb + ((size_t)((kv0) >> 5)) * 4096 + ii_ * 512 + l * 8, (dst) + ii_ * 512); } \
  __builtin_amdgcn_sched_barrier(0); } while (0)

#define WAIT_VM(n) do { asm volatile("s_waitcnt vmcnt(" #n ")" ::: "memory"); \
  __builtin_amdgcn_sched_barrier(0); } while (0)
#define WAIT_VM0 do { asm volatile("s_waitcnt vmcnt(0)" ::: "memory"); \
  __builtin_amdgcn_sched_barrier(0); } while (0)

// ---- fused diff-attention: 128-q blocks, 8 waves (qh4 x kvh2), 3-slot ring,
//      2-tile-deep prefetch, no-max softmax, permlane pack ----
__global__ __launch_bounds__(512, 2) void attn11_kernel(
    const u16* __restrict__ Qb, const u16* __restrict__ Kb, const u16* __restrict__ Vbt,
    const float* __restrict__ lq1, const float* __restrict__ lk1,
    const float* __restrict__ lq2, const float* __restrict__ lk2,
    const float* __restrict__ norm_w, u16* __restrict__ Xb)
{
  __shared__ __align__(16) u16 smem[49152];        // 96KB: K [2kvh][3 slots][4096] + V same at +24576
  __shared__ float stats[4][2][2][32];             // [qh][kvh][h][q] = L partial

  const int tid = threadIdx.x;
  const int w   = tid >> 6;
  const int l   = tid & 63;
  const int hi  = l >> 5;
  const int q   = l & 31;
  const int kvh = w & 1;        // compute kv half
  const int qh  = w >> 1;       // 0..3

  // staging job (independent of compute role): 8 waves cover 32 loads/tile
  const bool jK   = w < 4;
  const int  jrem = jK ? w : (w - 4);
  const int  jkvh = jrem >> 1;
  const int  jhalf= jrem & 1;
  const int  jkvb = jkvh * 1024;

  const int bid0 = blockIdx.x;
  const int bid = (bid0 & 7) * 32 + (bid0 >> 3);   // XCD swizzle (256 % 8 == 0)
  const int qt = bid & 15;
  const int he = (bid >> 4) & 3;
  const int b  = bid >> 6;
  const int q0 = qt * 128;
  const int bhe = b * 4 + he;
  const int qrow = q0 + qh * 32 + q;

  // lambda (per wave)
  float lp1 = lq1[l] * lk1[l], lp2 = lq2[l] * lk2[l];
  #pragma unroll
  for (int off = 32; off; off >>= 1) { lp1 += __shfl_xor(lp1, off); lp2 += __shfl_xor(lp2, off); }
  const float lam = __expf(lp1) - __expf(lp2) + LAMBDA_INIT;
  asm volatile("" :: "v"(lam));

  // Q fragments: B-operand (32x32x16): col=q, k = hi*8+j
  bf16x8 qf[2][4];
  {
    const u16* qp = Qb + ((size_t)(b * NN) + qrow) * DD + he * 128 + hi * 8;
    #pragma unroll
    for (int h = 0; h < 2; ++h)
      #pragma unroll
      for (int dk = 0; dk < 4; ++dk)
        qf[h][dk] = *(const bf16x8*)(qp + h * 64 + dk * 16);
  }
  WAIT_VM0;       // drain lambda+Q loads before counted pipeline
  #pragma unroll
  for (int h = 0; h < 2; ++h)
    #pragma unroll
    for (int dk = 0; dk < 4; ++dk)
      asm volatile("" :: "v"(qf[h][dk]));

  const u16* kgb = Kb + (size_t)bhe * NN * 128;
  const u16* vgb = Vbt + (size_t)bhe * 64 * 4096;

  // prologue: stage tiles 0,1 into slots 0,1 (4 loads each)
  #pragma unroll
  for (int pt = 0; pt < 2; ++pt) {
    u16* dst = (jK ? smem : smem + 24576) + (jkvh * 3 + pt) * 4096;
    if (jK) ISSUE_K4(dst, jkvb + pt * 32, jhalf);
    else    ISSUE_V4(dst, jkvb + pt * 32, jhalf);
  }

  f32x16 O[2][4];
  #pragma unroll
  for (int h = 0; h < 2; ++h)
    #pragma unroll
    for (int dt = 0; dt < 4; ++dt) O[h][dt] = fz16();
  float sl[2] = {0.f, 0.f};

  const int jq  = (q >> 1) & 7;
  const int dq1 = (q & 1) << 2;

  int scur = 0, spre = 2;   // scur = tt%3, spre = (tt+2)%3
  for (int tt = 0; tt < 32; ++tt) {
    WAIT_VM(4);                         // own tile-tt quartet landed (t+1's 4 in flight)
    __builtin_amdgcn_s_barrier();       // all 8 streams for tile tt landed
    __builtin_amdgcn_sched_barrier(0);

    {
      const int nt = (tt + 2) & 31;     // wrap-dummy at tail keeps vmcnt invariant
      u16* dst = (jK ? smem : smem + 24576) + (jkvh * 3 + spre) * 4096;
      if (jK) ISSUE_K4(dst, jkvb + nt * 32, jhalf);
      else    ISSUE_V4(dst, jkvb + nt * 32, jhalf);
    }

    const u16* Kcur = smem + (kvh * 3 + scur) * 4096;
    const u16* Vcur = smem + 24576 + (kvh * 3 + scur) * 4096;

    // ---- QK^T: S^T[kv][q], A=K LDS, B=Q regs ----
    f32x16 S[2];
    __builtin_amdgcn_s_setprio(1);
    #pragma unroll
    for (int h = 0; h < 2; ++h) {
      f32x16 acc = fz16();
      #pragma unroll
      for (int dk = 0; dk < 4; ++dk) {
        const int gd = h * 8 + dk * 2 + hi;
        const int g2 = (gd & 8) | ((gd & 7) ^ (q & 7));
        bf16x8 kf = *(const bf16x8*)&Kcur[q * 128 + g2 * 8];
        acc = __builtin_amdgcn_mfma_f32_32x32x16_bf16(kf, qf[h][dk], acc, 0, 0, 0);
      }
      S[h] = acc;
    }
    __builtin_amdgcn_s_setprio(0);

    // ---- no-max softmax: P = exp2(S); tree-sum partial L; permlane pack ----
    bf16x8 pb[2][2];
    #pragma unroll
    for (int h = 0; h < 2; ++h) {
      #pragma unroll
      for (int r = 0; r < 16; ++r)
        S[h][r] = __builtin_amdgcn_exp2f(S[h][r]);
      float y0 = (S[h][0]  + S[h][1])  + (S[h][2]  + S[h][3]);
      float y1 = (S[h][4]  + S[h][5])  + (S[h][6]  + S[h][7]);
      float y2 = (S[h][8]  + S[h][9])  + (S[h][10] + S[h][11]);
      float y3 = (S[h][12] + S[h][13]) + (S[h][14] + S[h][15]);
      sl[h] += (y0 + y1) + (y2 + y3);

      unsigned PK[8];
      #pragma unroll
      for (int p2 = 0; p2 < 8; ++p2)
        asm("v_cvt_pk_bf16_f32 %0, %1, %2" : "=v"(PK[p2]) : "v"(S[h][2*p2]), "v"(S[h][2*p2+1]));
      #pragma unroll
      for (int kb = 0; kb < 2; ++kb) {
        unsigned w0 = PK[4*kb + 0], w2v = PK[4*kb + 2];
        unsigned w1 = PK[4*kb + 1], w3v = PK[4*kb + 3];
        plswap(w0, w2v);
        plswap(w1, w3v);
        union { u32x4 u; bf16x8 v; } cv;
        cv.u = (u32x4){ w0, w1, w2v, w3v };
        pb[h][kb] = cv.v;
      }
    }

    // ---- PV: O^T[d][q] += V^T x P ----
    __builtin_amdgcn_s_setprio(1);
    #pragma unroll
    for (int kk = 0; kk < 2; ++kk)
      #pragma unroll
      for (int dt = 0; dt < 4; ++dt) {
        const int j = dt * 16 + (q >> 1);
        const int s8 = (dq1 + kk * 2 + hi) ^ jq;
        bf16x8 vf = *(const bf16x8*)&Vcur[j * 64 + s8 * 8];
        O[0][dt] = __builtin_amdgcn_mfma_f32_32x32x16_bf16(vf, pb[0][kk], O[0][dt], 0, 0, 0);
        O[1][dt] = __builtin_amdgcn_mfma_f32_32x32x16_bf16(vf, pb[1][kk], O[1][dt], 0, 0, 0);
      }
    __builtin_amdgcn_s_setprio(0);

    scur = (scur == 2) ? 0 : scur + 1;
    spre = (spre == 2) ? 0 : spre + 1;
  }

  WAIT_VM0;          // drain wrap-dummy prefetch before reusing LDS
  __syncthreads();

  // ---- cross-kv-half merge: plain sums ----
  const float slr0 = xhalf_add(sl[0]);   // full-exec
  const float slr1 = xhalf_add(sl[1]);
  if (hi == 0) {
    stats[qh][kvh][0][q] = slr0;
    stats[qh][kvh][1][q] = slr1;
  }
  __syncthreads();
  float L[2];
  #pragma unroll
  for (int h = 0; h < 2; ++h)
    L[h] = stats[qh][0][h][q] + stats[qh][1][h][q];

  // O merge in two qh-rounds (64KB xch each)
  float* xch = (float*)smem;
  #pragma unroll
  for (int qp = 0; qp < 2; ++qp) {
    const bool act = (qh >> 1) == qp;
    __syncthreads();
    if (act && kvh == 1) {
      #pragma unroll
      for (int h = 0; h < 2; ++h)
        #pragma unroll
        for (int dt = 0; dt < 4; ++dt)
          #pragma unroll
          for (int r = 0; r < 16; ++r)
            xch[(qh & 1) * 8192 + ((h * 4 + dt) * 16 + r) * 64 + l] = O[h][dt][r];
    }
    __syncthreads();
    if (act && kvh == 0) {
      #pragma unroll
      for (int h = 0; h < 2; ++h)
        #pragma unroll
        for (int dt = 0; dt < 4; ++dt)
          #pragma unroll
          for (int r = 0; r < 16; ++r)
            O[h][dt][r] += xch[(qh & 1) * 8192 + ((h * 4 + dt) * 16 + r) * 64 + l];
    }
  }
  __syncthreads();

  if (kvh == 0) {
    // ---- epilogue: diff, RMSNorm over d, store X bf16 ----
    const float i1 = 1.f / L[0];
    const float i2 = lam / L[1];
    float ss = 0.f;
    f32x16 od[4];
    #pragma unroll
    for (int dt = 0; dt < 4; ++dt)
      #pragma unroll
      for (int r = 0; r < 16; ++r) {
        float o = O[0][dt][r] * i1 - O[1][dt][r] * i2;
        od[dt][r] = o; ss += o * o;
      }
    ss += __shfl_xor(ss, 32);   // cross-half add ONLY (verified R14)
    const float rstd = rsqrtf(ss * (1.f / 128.f) + EPSV);
    const size_t xo = ((size_t)(b * NN) + qrow) * DD + he * 128;
    #pragma unroll
    for (int dt = 0; dt < 4; ++dt)
      #pragma unroll
      for (int rq = 0; rq < 4; ++rq) {
        const int d0 = dt * 32 + rq * 8 + hi * 4;
        const float4 nw = *(const float4*)&norm_w[d0];
        u16x4 ov;
        ov[0] = f2bf(od[dt][rq*4 + 0] * rstd * nw.x * 0.2f);
        ov[1] = f2bf(od[dt][rq*4 + 1] * rstd * nw.y * 0.2f);
        ov[2] = f2bf(od[dt][rq*4 + 2] * rstd * nw.z * 0.2f);
        ov[3] = f2bf(od[dt][rq*4 + 3] * rstd * nw.w * 0.2f);
        *(u16x4*)&Xb[xo + d0] = ov;
      }
  }
}

// ---- projection: bf16 MFMA, 64x64 tile, double-buffered ----
#define PLOAD(k0) do { \
    _Pragma("unroll") for (int p_ = 0; p_ < 2; ++p_) { \
      int idx_ = p_*256 + t; int r_ = idx_ >> 3, gi_ = idx_ & 7; \
      ra[p_] = *(const u16x8*)&Xb[(size_t)(row0 + r_) * DD + (k0) + gi_*8]; \
      rb[p_] = *(const u16x8*)&Wb[(size_t)(col0 + r_) * DD + (k0) + gi_*8]; } \
  } while (0)
#define PWRITE(bi) do { \
    _Pragma("unroll") for (int p_ = 0; p_ < 2; ++p_) { \
      int idx_ = p_*256 + t; int r_ = idx_ >> 3, gi_ = idx_ & 7; \
      *(u16x8*)&As[bi][r_*64 + ((gi_ ^ (r_ & 7)) << 3)] = ra[p_]; \
      *(u16x8*)&Bs[bi][r_*64 + ((gi_ ^ (r_ & 7)) << 3)] = rb[p_]; } \
  } while (0)

__global__ __launch_bounds__(256, 2) void proj_mfma_kernel(
    const u16* __restrict__ Xb, const u16* __restrict__ Wb,
    const float* __restrict__ bias, float* __restrict__ out)
{
  __shared__ __align__(16) u16 As[2][64*64];
  __shared__ __align__(16) u16 Bs[2][64*64];
  const int t = threadIdx.x;
  const int w = t >> 6, l = t & 63, g = l >> 4, c = l & 15;
  const int wm = w >> 1, wn = w & 1;
  const int row0 = blockIdx.x * 64, col0 = blockIdx.y * 64;

  u16x8 ra[2], rb[2];
  f32x4 acc[2][2];
  #pragma unroll
  for (int i = 0; i < 2; ++i)
    #pragma unroll
    for (int j = 0; j < 2; ++j) acc[i][j] = (f32x4){0,0,0,0};
  float bj[2];
  #pragma unroll
  for (int j = 0; j < 2; ++j) bj[j] = bias[col0 + wn*32 + j*16 + c];

  PLOAD(0);
  PWRITE(0);
  __syncthreads();
  for (int s = 0; s < 8; ++s) {
    const int bi = s & 1;
    if (s < 7) PLOAD((s + 1) * 64);
    #pragma unroll
    for (int kc = 0; kc < 2; ++kc) {
      bf16x8 af[2], bfv[2];
      #pragma unroll
      for (int i = 0; i < 2; ++i) {
        int rowa = wm*32 + i*16 + c;
        af[i]  = *(const bf16x8*)&As[bi][rowa*64 + (((kc*4 + g) ^ (c & 7)) << 3)];
        int rowb = wn*32 + i*16 + c;
        bfv[i] = *(const bf16x8*)&Bs[bi][rowb*64 + (((kc*4 + g) ^ (c & 7)) << 3)];
      }
      #pragma unroll
      for (int i = 0; i < 2; ++i)
        #pragma unroll
        for (int j = 0; j < 2; ++j)
          acc[i][j] = __builtin_amdgcn_mfma_f32_16x16x32_bf16(af[i], bfv[j], acc[i][j], 0, 0, 0);
    }
    if (s < 7) PWRITE((s + 1) & 1);
    __syncthreads();
  }
  #pragma unroll
  for (int i = 0; i < 2; ++i)
    #pragma unroll
    for (int j = 0; j < 2; ++j)
      #pragma unroll
      for (int rr = 0; rr < 4; ++rr)
        out[(size_t)(row0 + wm*32 + i*16 + g*4 + rr) * DD + col0 + wn*32 + j*16 + c] = acc[i][j][rr] + bj[j];
}

extern "C" void kernel_launch(void* const* d_in, const int* in_sizes, int n_in,
                              void* d_out, int out_size, void* d_ws, size_t ws_size,
                              hipStream_t stream) {
    const float* q      = (const float*)d_in[0];
    const float* k      = (const float*)d_in[1];
    const float* v      = (const float*)d_in[2];
    const float* lq1    = (const float*)d_in[3];
    const float* lk1    = (const float*)d_in[4];
    const float* lq2    = (const float*)d_in[5];
    const float* lk2    = (const float*)d_in[6];
    const float* norm_w = (const float*)d_in[7];
    const float* out_w  = (const float*)d_in[8];
    const float* out_b  = (const float*)d_in[9];
    float* out = (float*)d_out;

    u16* Qb  = (u16*)d_ws;                                   // 8 MB
    u16* Kb  = (u16*)((char*)d_ws + (8u  << 20));            // 8 MB
    u16* Vbt = (u16*)((char*)d_ws + (16u << 20));            // 8 MB
    u16* Wb  = (u16*)((char*)d_ws + (24u << 20));            // 0.5 MB
    u16* Xb  = (u16*)((char*)d_ws + (25u << 20));            // 8 MB

    prep_kernel<<<BB * NN + 256, 256, 0, stream>>>(q, k, out_w, Qb, Kb, Wb);
    v_prep_kernel<<<dim3(32, 2, 16), 256, 0, stream>>>(v, Vbt);
    attn11_kernel<<<256, 512, 0, stream>>>(Qb, Kb, Vbt, lq1, lk1, lq2, lk2, norm_w, Xb);
    proj_mfma_kernel<<<dim3(128, 8), 256, 0, stream>>>(Xb, Wb, out_b, out);
}